// Round 18
// baseline (93.325 us; speedup 1.0000x reference)
//
#include <hip/hip_runtime.h>
#include <hip/hip_bf16.h>

#define BB 64
#define TT 32768
#define KK 256
#define LL 2065          // conv out length
#define LT1 64           // k1 cols per block
#define NLT1 33          // ceil(LL/64)
#define NP1 (BB*NLT1)    // 2112 slot-major partial rows
#define NJ 19            // j-range for synthesis (P4 packing)
#define NPT3 8           // k3 P-tiles per batch (64 packed positions each)

typedef __attribute__((ext_vector_type(8))) short short8;
typedef __attribute__((ext_vector_type(4))) float f32x4;
typedef __attribute__((ext_vector_type(4))) int int4v;
typedef __attribute__((ext_vector_type(2))) unsigned int uint2v;

__device__ __forceinline__ unsigned short f2bf(float f) {
    unsigned u = __builtin_bit_cast(unsigned, f);
    unsigned r = (u + 0x7FFFu + ((u >> 16) & 1u)) >> 16;
    return (unsigned short)r;
}
__device__ __forceinline__ unsigned pkbf(float a, float b) {
    unsigned r;
    asm("v_cvt_pk_bf16_f32 %0, %1, %2" : "=v"(r) : "v"(a), "v"(b));
    return r;
}
__device__ __forceinline__ float bf2f(unsigned short v) {
    return __builtin_bit_cast(float, (unsigned)v << 16);
}
// async global->LDS, 16B per lane
__device__ __forceinline__ void gload_lds16(const void* g, void* l) {
    __builtin_amdgcn_global_load_lds(
        (const __attribute__((address_space(1))) unsigned int*)g,
        (__attribute__((address_space(3))) unsigned int*)l, 16, 0, 0);
}
// slot permutation: h slot s holds conv channel pi(s)
__device__ __forceinline__ int slot_pi(int s) {
    int gg = s >> 4, f = s & 15;
    if (f < 8)  return 128 + 8*gg + f;
    if (f < 12) return 64 + 4*gg + (f - 8);
    if (f < 14) return 32 + 2*gg + (f - 12);
    if (f == 14) return 16 + gg;
    return gg;
}

// ---------------- k0s: per-lane sparse gated-Haar weights Wpf[16][144] + cbsp[256] ----
// lane g, entry e = lvl*16+m: tap j = 16g+m of channel o(lvl,g,m); cs prefolded.
__global__ void k0s_wpf(const float* __restrict__ cw, const float* __restrict__ cgt,
                        const float* __restrict__ cs, const float* __restrict__ cb,
                        float* __restrict__ Wpf, float* __restrict__ cbsp)
{
    int idx = blockIdx.x*256 + threadIdx.x;    // 2304 = 9*256
    if (idx < 2304) {
        int g = idx / 144, e = idx - g*144;
        int lvl = e >> 4, m = e & 15;
        int j = 16*g + m;
        int o;
        switch (lvl) {
            case 0: o = 0; break;
            case 1: o = 1; break;
            case 2: o = 2 + (g>>3); break;
            case 3: o = 4 + (g>>2); break;
            case 4: o = 8 + (g>>1); break;
            case 5: o = 16 + g; break;
            case 6: o = 32 + 2*g + (m>>3); break;
            case 7: o = 64 + 4*g + (m>>2); break;
            default: o = 128 + 8*g + (m>>1); break;
        }
        Wpf[idx] = cs[o] * cw[o*KK + j] * (cgt[o*KK + j] + 1.0f) * 0.5f;
    }
    if (blockIdx.x == 0) {
        int s = threadIdx.x;
        int o = slot_pi(s);
        cbsp[s] = cs[o]*cb[o];
    }
}

// ---------------- k1: sparse-Haar analysis conv (fp32 VALU), slot-permuted h ---------
// 256 thr = 4 waves; wave w owns cols 16w..16w+15; iter = 4 cols (16 lanes each).
// Lane (cg,g): taps 16g..16g+15 of col. Fine levels 5-8 in-lane; levels 0-4 butterfly.
__global__ __launch_bounds__(256, 2)
void k1_conv(const float* __restrict__ x, const float* __restrict__ Wpf,
             const float* __restrict__ cbsp,
             unsigned short* __restrict__ hout,
             float* __restrict__ psum, float* __restrict__ psq)
{
    __shared__ __align__(16) float xs[80*20];             // 6400 B padded x grid
    __shared__ __align__(16) unsigned short hb[64*256];   // 32768 B, chunk-swizzled
    __shared__ float redS[8*256];                         // 8192 B
    __shared__ float redQ[8*256];                         // 8192 B -> total 55552 B

    const int tid   = threadIdx.x;
    const int ltile = blockIdx.x;
    const int b     = blockIdx.y;
    const int l0    = ltile * LT1;
    const int lane  = tid & 63;
    const int w     = tid >> 6;
    const int gp    = lane & 15;
    const int cg    = lane >> 4;

    // stage x into padded grid: grid[r][m] = x[pos0 + 16r + m], stride 20 floats
    {
        const float* xb = x + (size_t)b*TT;
        const long pos0 = (long)l0*16 - 256;
        #pragma unroll
        for (int i = 0; i < 5; ++i) {
            int it = tid + i*256;
            long p = pos0 + it;
            xs[(it>>4)*20 + (it&15)] = (p >= 0 && p < TT) ? xb[p] : 0.0f;
        }
    }

    // per-lane weights (144) and fine biases (16)
    float wv[144];
    {
        const f32x4* wsrc = (const f32x4*)(Wpf + gp*144);
        #pragma unroll
        for (int i = 0; i < 36; ++i) {
            f32x4 t = wsrc[i];
            wv[4*i] = t[0]; wv[4*i+1] = t[1]; wv[4*i+2] = t[2]; wv[4*i+3] = t[3];
        }
    }
    f32x4 cbf[4];
    #pragma unroll
    for (int i = 0; i < 4; ++i) cbf[i] = *(const f32x4*)(cbsp + gp*16 + 4*i);

    // coarse writer: lane gp writes row wrow (bijection; lane holds it post-butterfly)
    const int wrow = (gp & 1) ? (8 + (gp >> 1))
                              : ((4056416 >> (3*(gp >> 1))) & 7);  // {0,4,5,2,6,3,7,1}
    const float cbcoarse = cbsp[16*wrow + 15];
    __syncthreads();

    #pragma unroll 1
    for (int it = 0; it < 4; ++it) {
        const int col = w*16 + it*4 + cg;
        float xr[16];
        {
            const f32x4* xp = (const f32x4*)&xs[(col + gp)*20];
            #pragma unroll
            for (int i = 0; i < 4; ++i) {
                f32x4 t = xp[i];
                xr[4*i] = t[0]; xr[4*i+1] = t[1]; xr[4*i+2] = t[2]; xr[4*i+3] = t[3];
            }
        }
        // coarse partials (levels 0-4)
        float p0 = 0.f, p1 = 0.f, p2 = 0.f, p3 = 0.f, p4 = 0.f;
        #pragma unroll
        for (int m = 0; m < 16; ++m) {
            p0 = fmaf(wv[m],      xr[m], p0);
            p1 = fmaf(wv[16 + m], xr[m], p1);
            p2 = fmaf(wv[32 + m], xr[m], p2);
            p3 = fmaf(wv[48 + m], xr[m], p3);
            p4 = fmaf(wv[64 + m], xr[m], p4);
        }
        // butterflies within 16-lane groups
        p4 += __shfl_xor(p4, 1);
        p3 += __shfl_xor(p3, 1); p3 += __shfl_xor(p3, 2);
        p2 += __shfl_xor(p2, 1); p2 += __shfl_xor(p2, 2); p2 += __shfl_xor(p2, 4);
        p1 += __shfl_xor(p1, 1); p1 += __shfl_xor(p1, 2); p1 += __shfl_xor(p1, 4);
        p1 += __shfl_xor(p1, 8);
        p0 += __shfl_xor(p0, 1); p0 += __shfl_xor(p0, 2); p0 += __shfl_xor(p0, 4);
        p0 += __shfl_xor(p0, 8);

        // fine levels (in-lane)
        float v8[8], v7[4], v6[2], v5 = 0.f;
        #pragma unroll
        for (int k = 0; k < 8; ++k)
            v8[k] = fmaf(wv[128 + 2*k + 1], xr[2*k + 1], wv[128 + 2*k]*xr[2*k]);
        #pragma unroll
        for (int k = 0; k < 4; ++k) {
            float a = wv[112 + 4*k]*xr[4*k];
            a = fmaf(wv[112 + 4*k + 1], xr[4*k + 1], a);
            a = fmaf(wv[112 + 4*k + 2], xr[4*k + 2], a);
            v7[k] = fmaf(wv[112 + 4*k + 3], xr[4*k + 3], a);
        }
        #pragma unroll
        for (int k = 0; k < 2; ++k) {
            float a = 0.f;
            #pragma unroll
            for (int m = 0; m < 8; ++m) a = fmaf(wv[96 + 8*k + m], xr[8*k + m], a);
            v6[k] = a;
        }
        #pragma unroll
        for (int m = 0; m < 16; ++m) v5 = fmaf(wv[80 + m], xr[m], v5);

        // bias + relu + pack + swizzled hb writes
        const int swz = col & 7;
        unsigned short* hcol = hb + col*256;
        {
            float h0 = fmaxf(v8[0] + cbf[0][0], 0.f), h1 = fmaxf(v8[1] + cbf[0][1], 0.f);
            float h2 = fmaxf(v8[2] + cbf[0][2], 0.f), h3 = fmaxf(v8[3] + cbf[0][3], 0.f);
            float h4 = fmaxf(v8[4] + cbf[1][0], 0.f), h5 = fmaxf(v8[5] + cbf[1][1], 0.f);
            float h6 = fmaxf(v8[6] + cbf[1][2], 0.f), h7 = fmaxf(v8[7] + cbf[1][3], 0.f);
            int4v pk = { (int)pkbf(h0,h1), (int)pkbf(h2,h3),
                         (int)pkbf(h4,h5), (int)pkbf(h6,h7) };
            *(int4v*)(hcol + (((2*gp) ^ swz) << 3)) = pk;      // slots f0-7
        }
        {
            unsigned short* c1 = hcol + (((2*gp + 1) ^ swz) << 3);
            float h0 = fmaxf(v7[0] + cbf[2][0], 0.f), h1 = fmaxf(v7[1] + cbf[2][1], 0.f);
            float h2 = fmaxf(v7[2] + cbf[2][2], 0.f), h3 = fmaxf(v7[3] + cbf[2][3], 0.f);
            uint2v pk2 = { pkbf(h0,h1), pkbf(h2,h3) };
            *(uint2v*)c1 = pk2;                                 // slots f8-11
            float h4 = fmaxf(v6[0] + cbf[3][0], 0.f), h5 = fmaxf(v6[1] + cbf[3][1], 0.f);
            *(unsigned*)(c1 + 4) = pkbf(h4, h5);                // slots f12-13
            float h6 = fmaxf(v5 + cbf[3][2], 0.f);
            c1[6] = (unsigned short)(pkbf(h6, h6) & 0xffffu);   // slot f14
        }
        {
            // coarse row wrow -> slot 16*wrow+15
            float pc;
            if (gp & 1) pc = p4;
            else pc = (wrow == 0) ? p0 : (wrow == 1) ? p1
                     : (wrow <= 3) ? p2 : p3;
            float hc = fmaxf(pc + cbcoarse, 0.f);
            unsigned short* cc = hcol + (((2*wrow + 1) ^ swz) << 3);
            cc[7] = (unsigned short)(pkbf(hc, hc) & 0xffffu);
        }
    }
    __syncthreads();

    // writeback (unswizzle) + BN partials per slot-octet
    float s8[8], q8[8];
    #pragma unroll
    for (int j = 0; j < 8; ++j) { s8[j] = 0.f; q8[j] = 0.f; }
    const int chunk = tid & 31;        // 16B chunk = slots 8*chunk..+7
    const int colb  = tid >> 5;        // col subset: colb + 8k
    #pragma unroll
    for (int k = 0; k < 8; ++k) {
        int col = colb + k*8;
        int l = l0 + col;
        if (l < LL) {
            int4v v = *(const int4v*)(hb + col*256 + ((chunk ^ (col & 7)) << 3));
            *(int4v*)(hout + (((size_t)(b*LL + l)) << 8) + chunk*8) = v;
            #pragma unroll
            for (int i = 0; i < 4; ++i) {
                unsigned uu = (unsigned)v[i];
                float f0 = bf2f((unsigned short)(uu & 0xffffu));
                float f1 = bf2f((unsigned short)(uu >> 16));
                s8[2*i] += f0;   q8[2*i]   = fmaf(f0, f0, q8[2*i]);
                s8[2*i+1] += f1; q8[2*i+1] = fmaf(f1, f1, q8[2*i+1]);
            }
        }
    }
    {
        f32x4 a0 = { s8[0], s8[1], s8[2], s8[3] }, a1 = { s8[4], s8[5], s8[6], s8[7] };
        f32x4 b0 = { q8[0], q8[1], q8[2], q8[3] }, b1 = { q8[4], q8[5], q8[6], q8[7] };
        *(f32x4*)&redS[colb*256 + chunk*8]     = a0;
        *(f32x4*)&redS[colb*256 + chunk*8 + 4] = a1;
        *(f32x4*)&redQ[colb*256 + chunk*8]     = b0;
        *(f32x4*)&redQ[colb*256 + chunk*8 + 4] = b1;
    }
    __syncthreads();
    {
        float s = 0.f, q = 0.f;
        #pragma unroll
        for (int k = 0; k < 8; ++k) {
            s += redS[k*256 + tid];
            q += redQ[k*256 + tid];
        }
        size_t base = ((size_t)(b*NLT1 + ltile)) << 8;
        psum[base + tid] = s;
        psq [base + tid] = q;
    }
}

// ---------------- k2: BN stats (slot c) -> folded synthesis weights W3s[k][c] + SWS --
__global__ __launch_bounds__(256)
void k2_bn(const float* __restrict__ psum, const float* __restrict__ psq,
           const float* __restrict__ bng, const float* __restrict__ bnb,
           const float* __restrict__ ctw, const float* __restrict__ ctg,
           const float* __restrict__ ctscale,
           float* __restrict__ W3s, float* __restrict__ SWS)
{
    __shared__ double rs[4], rq[4];
    __shared__ float s_a, s_bc;
    __shared__ float swl[256];
    const int c = blockIdx.x;           // slot
    const int tid = threadIdx.x;
    const int o = slot_pi(c);           // original conv channel
    double s = 0.0, q = 0.0;
    for (int i = tid; i < NP1; i += 256) {
        s += (double)psum[((size_t)i << 8) + c];
        q += (double)psq [((size_t)i << 8) + c];
    }
    for (int off = 32; off > 0; off >>= 1) {
        s += __shfl_down(s, off);
        q += __shfl_down(q, off);
    }
    if ((tid & 63) == 0) { rs[tid >> 6] = s; rq[tid >> 6] = q; }
    __syncthreads();
    if (tid == 0) {
        double st = rs[0]+rs[1]+rs[2]+rs[3];
        double qt = rq[0]+rq[1]+rq[2]+rq[3];
        const double cnt = (double)BB * (double)LL;
        double mu = st / cnt;
        double var = qt / cnt - mu*mu;
        float rsig = (float)(1.0 / sqrt(var + 1e-5));
        float a = bng[o] * rsig;
        s_a = a;
        s_bc = bnb[o] - (float)mu * a;
    }
    __syncthreads();
    float a = s_a, bc = s_bc, scl = ctscale[0];
    int gi = o*KK + tid;                          // k = tid
    float wt = ctw[gi] * (ctg[gi] + 1.0f) * 0.5f;
    W3s[tid*KK + c] = scl * a * wt;
    swl[tid] = wt * bc;
    __syncthreads();
    if (tid < 16) {
        float acc2 = 0.0f;
        #pragma unroll
        for (int d = 0; d < 16; ++d) acc2 += swl[d*16 + tid];
        SWS[c*16 + tid] = acc2;
    }
}

__global__ __launch_bounds__(256)
void k2b_const(const float* __restrict__ SWS, const float* __restrict__ ctb,
               const float* __restrict__ ctscale, float* __restrict__ C2)
{
    __shared__ float accb[16][17];
    int tid = threadIdx.x;
    int r = tid & 15, cc = tid >> 4;
    float s = 0.0f;
    #pragma unroll
    for (int i = 0; i < 16; ++i) s += SWS[(cc*16 + i)*16 + r];
    accb[cc][r] = s;
    __syncthreads();
    if (tid < 16) {
        float t = 0.0f;
        #pragma unroll
        for (int i = 0; i < 16; ++i) t += accb[i][tid];
        C2[tid] = ctscale[0] * (t + ctb[0]);
    }
}

// ---------------- k2c: B2f fragment table for synthesis ----------------
__global__ void k2c_b2f(const float* __restrict__ W3s, unsigned short* __restrict__ B2f)
{
    int idx = blockIdx.x*256 + threadIdx.x;        // 38912 threads
    int lane = idx & 63;
    int ntG  = (idx>>6) & 3;
    int kk   = (idx>>8) & 7;
    int j    = idx>>11;
    int c    = kk*32 + ((lane>>4)<<3);
    int r    = lane & 15;
    int d    = ntG + 15 - j;
    short8 v;
    if (d >= 0 && d <= 15) {
        const float* wr = W3s + (size_t)(16*d + r)*KK + c;
        #pragma unroll
        for (int i = 0; i < 8; ++i) v[i] = (short)f2bf(wr[i]);
    } else {
        #pragma unroll
        for (int i = 0; i < 8; ++i) v[i] = 0;
    }
    *(short8*)(B2f + (size_t)idx*8) = v;
}

// ---------------- k3: synthesis conv, j-partitioned waves [R11 champion] ------------
__global__ __launch_bounds__(512, 1)
void k3_synth(const unsigned short* __restrict__ h, const unsigned short* __restrict__ B2f,
              const float* __restrict__ C2, float* __restrict__ out)
{
    __shared__ __align__(16) char As[272*512];    // 139264 B; red[8][64][68] aliases after
    const int tid  = threadIdx.x;
    const int lane = tid & 63;
    const int w    = tid >> 6;       // 0..7
    const int b    = blockIdx.y;
    const int P0   = blockIdx.x * 64;

    const char* hbase = (const char*)h + (((size_t)(b*LL) + 4*P0 + 1) << 9);

    {
        const int rl = lane >> 5;
        #pragma unroll
        for (int i = 0; i < 17; ++i) {
            int r0  = w*34 + i*2;
            int row = r0 + rl;
            int chunk = (lane & 31) ^ ((row >> 2) & 7);
            gload_lds16(hbase + (size_t)row*512 + chunk*16, As + r0*512);
        }
    }
    __syncthreads();

    const int li = lane & 15;
    const int gq = lane >> 4;

    f32x4 acc[4][4];
    #pragma unroll
    for (int mt = 0; mt < 4; ++mt)
        #pragma unroll
        for (int nt = 0; nt < 4; ++nt) acc[mt][nt] = (f32x4){0.f,0.f,0.f,0.f};

    #pragma unroll 1
    for (int jj = 0; jj < 3; ++jj) {
        const int j = w + jj*8;
        if (j >= NJ) break;
        short8 bfA[4], bfB[4];
        #pragma unroll
        for (int nt = 0; nt < 4; ++nt)
            bfA[nt] = *(const short8*)(B2f + (((size_t)(j*8 + 0)*4 + nt)*64 + lane)*8);
        #pragma unroll
        for (int kk = 0; kk < 8; ++kk) {
            if (kk < 7) {
                #pragma unroll
                for (int nt = 0; nt < 4; ++nt)
                    bfB[nt] = *(const short8*)(B2f + (((size_t)(j*8 + kk+1)*4 + nt)*64 + lane)*8);
            }
            short8 af[4];
            #pragma unroll
            for (int mt = 0; mt < 4; ++mt) {
                int row = 64*mt + 4*li + j;
                int p = (kk*4 + gq) ^ ((row >> 2) & 7);
                af[mt] = *(const short8*)(As + row*512 + p*16);
            }
            __builtin_amdgcn_s_setprio(1);
            #pragma unroll
            for (int mt = 0; mt < 4; ++mt)
                #pragma unroll
                for (int nt = 0; nt < 4; ++nt)
                    acc[mt][nt] = __builtin_amdgcn_mfma_f32_16x16x32_bf16(af[mt], bfA[nt], acc[mt][nt], 0, 0, 0);
            __builtin_amdgcn_s_setprio(0);
            #pragma unroll
            for (int nt = 0; nt < 4; ++nt) bfA[nt] = bfB[nt];
        }
    }
    __syncthreads();

    float* red = (float*)As;
    #pragma unroll
    for (int mt = 0; mt < 4; ++mt)
        #pragma unroll
        for (int nt = 0; nt < 4; ++nt) {
            int u = nt*16 + li;
            #pragma unroll
            for (int rr = 0; rr < 4; ++rr) {
                int Pl = 16*mt + gq*4 + rr;
                red[w*4352 + Pl*68 + u] = acc[mt][nt][rr];
            }
        }
    __syncthreads();

    {
        float* ob = out + (size_t)b*TT + (size_t)P0*64;
        #pragma unroll
        for (int it = 0; it < 2; ++it) {
            int item = it*512 + tid;
            int P = item >> 4, uq = item & 15;
            f32x4 s = (f32x4){0.f,0.f,0.f,0.f};
            #pragma unroll
            for (int c = 0; c < 8; ++c)
                s += *(const f32x4*)&red[c*4352 + P*68 + uq*4];
            int ub = (uq & 3)*4;
            f32x4 c2v = { C2[ub], C2[ub+1], C2[ub+2], C2[ub+3] };
            *(f32x4*)&ob[P*64 + uq*4] = s + c2v;
        }
    }
}

extern "C" void kernel_launch(void* const* d_in, const int* in_sizes, int n_in,
                              void* d_out, int out_size, void* d_ws, size_t ws_size,
                              hipStream_t stream)
{
    const float* x       = (const float*)d_in[0];
    const float* cw      = (const float*)d_in[1];
    const float* cb      = (const float*)d_in[2];
    const float* cgt     = (const float*)d_in[3];
    const float* cs      = (const float*)d_in[4];
    const float* bng     = (const float*)d_in[5];
    const float* bnb     = (const float*)d_in[6];
    const float* ctw     = (const float*)d_in[7];
    const float* ctb     = (const float*)d_in[8];
    const float* ctg     = (const float*)d_in[9];
    const float* ctscale = (const float*)d_in[10];
    float* out = (float*)d_out;

    char* ws = (char*)d_ws;
    size_t off = 0;
    unsigned short* h    = (unsigned short*)(ws + off); off += (size_t)BB*LL*KK*2;
    float* psum          = (float*)(ws + off);          off += (size_t)NP1*KK*4;   // 2.16 MB
    float* psq           = (float*)(ws + off);          off += (size_t)NP1*KK*4;
    float* W3s           = (float*)(ws + off);          off += (size_t)KK*KK*4;
    float* SWS           = (float*)(ws + off);          off += (size_t)KK*16*4;
    float* C2            = (float*)(ws + off);          off += 64;
    float* Wpf           = (float*)(ws + off);          off += 2304*4;
    float* cbsp          = (float*)(ws + off);          off += 256*4;
    unsigned short* B2f  = (unsigned short*)(ws + off); off += (size_t)NJ*8*4*64*8*2;

    k0s_wpf <<<9, 256, 0, stream>>>(cw, cgt, cs, cb, Wpf, cbsp);
    k1_conv <<<dim3(NLT1, BB), 256, 0, stream>>>(x, Wpf, cbsp, h, psum, psq);
    k2_bn   <<<KK, 256, 0, stream>>>(psum, psq, bng, bnb, ctw, ctg, ctscale, W3s, SWS);
    k2b_const<<<1, 256, 0, stream>>>(SWS, ctb, ctscale, C2);
    k2c_b2f <<<152, 256, 0, stream>>>(W3s, B2f);
    k3_synth<<<dim3(NPT3, BB), 512, 0, stream>>>(h, B2f, C2, out);
}